// Round 11
// baseline (1287.806 us; speedup 1.0000x reference)
//
#include <hip/hip_runtime.h>
#include <cstdint>
#include <cstddef>

typedef unsigned short u16;
typedef unsigned int u32;
typedef __attribute__((ext_vector_type(8))) short short8;
typedef __attribute__((ext_vector_type(4))) float floatx4;
typedef __attribute__((ext_vector_type(2))) float float2v;

#define NROWS 38400   // B*T = 64*600

// ---- workspace layout (bytes) ----
#define OFF_FLAG 0u
#define OFF_GI   64u           // (unused after g1 fusion; kept for layout stability)
#define OFF_HCAT 36864064u     // [38400][80] f32    = 12,288,000
#define OFF_B1A  49152064u     // [2][128][576] bf16 =    294,912
#define OFF_B1B  49446976u     // [2][128][576] bf16 =    294,912
#define OFF_B2   49741888u     // [80][1472] bf16    =    235,520
#define OFF_B3   49977408u     // [272][1472] bf16   =    800,768  (end ~50.78 MB)

template<int N> struct IC { static constexpr int v = N; };

__device__ inline float bf2f(u16 u){ union{u32 i; float f;} v; v.i = ((u32)u)<<16; return v.f; }
__device__ inline u16 f2bf(float f){
  u32 u = __float_as_uint(f);
  return (u16)((u + 0x7FFFu + ((u>>16)&1u)) >> 16);   // RNE
}
__device__ inline float lodf(const void* p, size_t i, int isbf){
  return isbf ? bf2f(((const u16*)p)[i]) : ((const float*)p)[i];
}
__device__ inline float rcpf(float x){ return __builtin_amdgcn_rcpf(x); }
__device__ inline float sigm(float x){ return rcpf(1.0f+__expf(-x)); }
__device__ inline float tanh_(float x){
  float e = __expf(-2.0f*fabsf(x)); float t = (1.0f-e)*rcpf(1.0f+e); return x<0.f ? -t : t;
}

// ============================= detect input dtype (bf16 vs f32) =============================
__global__ void detect_kernel(const u16* __restrict__ xx, int* __restrict__ flag){
  const int l = threadIdx.x;
  const u16 w = xx[2*l];
  const int e = (w>>7)&0xFF;
  const unsigned long long m = __ballot(e >= 100 && e <= 133);
  if (l == 0) *flag = (__popcll(m) >= 32) ? 1 : 0;   // 1 = bf16
}

// ============================= prep: build padded bf16 B^T matrices =============================
// B1a/B1b now laid out as TWO 128-row panels (d=0: f0Wih, d=1: b0Wih), each
// tile-aligned for the fused in-gru MFMA (rows 120..127 zero).
__global__ void prep_kernel(const void* __restrict__ f0Wih, const void* __restrict__ b0Wih,
                            const void* __restrict__ k1b, const void* __restrict__ k1s, const void* __restrict__ k1sc,
                            const void* __restrict__ k2b, const void* __restrict__ k2s, const void* __restrict__ k2sc,
                            const int* __restrict__ flag,
                            u16* __restrict__ B1a, u16* __restrict__ B1b,
                            u16* __restrict__ B2, u16* __restrict__ B3)
{
  const int isbf = *flag;
  const int idx = blockIdx.x*256 + threadIdx.x;
  if (idx < 73728){
    const int j = idx/288, k = idx - j*288;       // j 0..255, k 0..287
    const int d = j>>7, jj = j&127;
    float w = 0.f;
    if (k < 257 && jj < 120)
      w = d ? lodf(b0Wih, (size_t)jj*257+k, isbf) : lodf(f0Wih, (size_t)jj*257+k, isbf);
    const u16 hi = f2bf(w); const u16 lo = f2bf(w - bf2f(hi));
    B1a[(size_t)j*576 + 2*k] = hi; B1a[(size_t)j*576 + 2*k+1] = hi;
    B1b[(size_t)j*576 + 2*k] = lo; B1b[(size_t)j*576 + 2*k+1] = 0;
  } else if (idx < 132608){
    const int t = idx - 73728; const int n = t/736, m = t - n*736;
    float v = 0.f;
    if (m < 80) v = lodf(k1b, (size_t)n*80+m, isbf);
    else if (m >= 96){ const int m2 = m-96, i = m2>>3, g = m2&7;
      v = lodf(k1s, ((size_t)n*80+i)*8+g, isbf) * lodf(k1sc, (size_t)n*80+i, isbf); }
    const u16 vv = f2bf(v);
    B2[(size_t)n*1472 + 2*m] = vv; B2[(size_t)n*1472 + 2*m+1] = vv;
  } else {
    const int t = idx - 132608; const int n = t/736, m = t - n*736;
    float v = 0.f;
    if (n < 257){
      if (m < 80) v = lodf(k2b, (size_t)n*80+m, isbf);
      else if (m >= 96){ const int m2 = m-96, i = m2>>3, g = m2&7;
        v = lodf(k2s, ((size_t)n*80+i)*8+g, isbf) * lodf(k2sc, (size_t)n*80+i, isbf); }
    }
    const u16 vv = f2bf(v);
    B3[(size_t)n*1472 + 2*m] = vv; B3[(size_t)n*1472 + 2*m+1] = vv;
  }
}

// ============================= GRU with fused G1 =============================
// R11: g1_kernel ELIMINATED. gru's stager wave (w3) had ~80% idle slack; it now
// COMPUTES each 32-tick gi chunk via MFMA (x @ Wih^T + bih, same hi/lo bf16
// split and same accumulation order as g1 -> bit-identical gi) directly into
// chunkbuf, spread over the 8 iterations of each chunk window (2-3 K-steps per
// iteration, ~1.5K cy against 3.2K cy slack). Kills the 36.9MB gi HBM write +
// re-read and the separate g1 dispatch. Consumers never read OOB chunk rows,
// so clamped x loads are safe (garbage rows unread, verified both directions).
#define PIN_W() do { \
    _Pragma("unroll") \
    for (int k_ = 0; k_ < 20; ++k_) \
      asm volatile("" : "+v"(WA[k_]), "+v"(WB[k_]), "+v"(WC[k_])); \
    asm volatile("" : "+v"(bA), "+v"(bB), "+v"(bC)); \
  } while (0)

__launch_bounds__(256, 1)
__global__ void gru_kernel(const void* __restrict__ x,
  const u16* __restrict__ B1a, const u16* __restrict__ B1b,
  const void* __restrict__ f0bih, const void* __restrict__ b0bih,
  const void* __restrict__ f0Whh, const void* __restrict__ f0bhh,
  const void* __restrict__ f1Wih, const void* __restrict__ f1Whh, const void* __restrict__ f1bih, const void* __restrict__ f1bhh,
  const void* __restrict__ b0Whh, const void* __restrict__ b0bhh,
  const void* __restrict__ b1Wih, const void* __restrict__ b1Whh, const void* __restrict__ b1bih, const void* __restrict__ b1bhh,
  const int* __restrict__ flag, float* __restrict__ hcat)
{
  __shared__ int4 chunkbuf[2][960];                                   // 30720 B: [2][32 ticks][120 f32]
  __shared__ __attribute__((aligned(16))) float hbuf[2][64][40];      // 20480 B
  __shared__ __attribute__((aligned(16))) float h0buf[2][4][40];      // 1280 B
  __shared__ __attribute__((aligned(16))) float gi1buf[2][4][3][40];  // 3840 B
  __shared__ __attribute__((aligned(16))) float h0st[40];             // layer0 h state (broadcast row)
  __shared__ __attribute__((aligned(16))) float h1st[40];             // layer1 h state
  const int isbf = *flag;
  const int tid = threadIdx.x, l = tid&63;
  const int w = __builtin_amdgcn_readfirstlane(tid) >> 6;
  const int blk = blockIdx.x, d = blk>>6, bat = blk&63;
  const int li = (l < 40) ? l : 39;
  const int m16 = l&15, q4 = l>>4;

  if (w == 3){
    // ---------------- fused G1 producer + hcat flusher ----------------
    const u16* B1ad = B1a + (size_t)(d ? 128 : 0)*576;
    const u16* B1bd = B1b + (size_t)(d ? 128 : 0)*576;
    const void* bihd = d ? b0bih : f0bih;
    float bias_v[8];
    #pragma unroll
    for (int nt=0; nt<8; ++nt){
      const int col = nt*16 + m16;
      bias_v[nt] = (col < 120) ? lodf(bihd, col, isbf) : 0.f;
    }
    const long long xrow0 = (long long)bat*600;

    floatx4 acc[2][8];

    auto acc_zero = [&](){
      #pragma unroll
      for (int mt=0;mt<2;++mt)
        #pragma unroll
        for (int nt=0;nt<8;++nt){ floatx4 z={0.f,0.f,0.f,0.f}; acc[mt][nt]=z; }
    };
    // a-frag: lane(m16,q4) holds virtual-k [ks*32+q4*8 .. +7] of tick row
    // (tick0 + mt*16 + m16): interleaved (hi,lo) of 4 real cols.
    auto afrag = [&](int tick0, int mt, int ks) -> short8 {
      int t = tick0 + mt*16 + m16;
      t = (t < 0) ? 0 : (t > 599 ? 599 : t);     // clamp: garbage rows never read
      const size_t xb = (size_t)(xrow0 + t)*257;
      short8 af;
      #pragma unroll
      for (int cj=0; cj<4; ++cj){
        const int col = ks*16 + q4*4 + cj;
        const float v = (col < 257) ? lodf(x, xb + col, isbf) : 0.f;
        const u16 hi = f2bf(v);
        af[2*cj]   = (short)hi;
        af[2*cj+1] = (short)f2bf(v - bf2f(hi));
      }
      return af;
    };
    auto chunk_ks = [&](int c, int k0, int k1){
      const int tick0 = d ? (568 - 32*c) : (32*c);
      #pragma unroll 1
      for (int ks=k0; ks<k1; ++ks){
        const short8 af0 = afrag(tick0, 0, ks);
        const short8 af1 = afrag(tick0, 1, ks);
        #pragma unroll
        for (int nt=0; nt<8; ++nt){
          const short8 ba = *(const short8*)&B1ad[(size_t)(nt*16+m16)*576 + ks*32 + q4*8];
          acc[0][nt] = __builtin_amdgcn_mfma_f32_16x16x32_bf16(af0, ba, acc[0][nt], 0, 0, 0);
          acc[1][nt] = __builtin_amdgcn_mfma_f32_16x16x32_bf16(af1, ba, acc[1][nt], 0, 0, 0);
          if (!isbf){
            const short8 bb = *(const short8*)&B1bd[(size_t)(nt*16+m16)*576 + ks*32 + q4*8];
            acc[0][nt] = __builtin_amdgcn_mfma_f32_16x16x32_bf16(af0, bb, acc[0][nt], 0, 0, 0);
            acc[1][nt] = __builtin_amdgcn_mfma_f32_16x16x32_bf16(af1, bb, acc[1][nt], 0, 0, 0);
          }
        }
      }
    };
    auto chunk_store = [&](int c){
      float* dst = (float*)&chunkbuf[c&1][0];
      #pragma unroll
      for (int mt=0; mt<2; ++mt){
        #pragma unroll
        for (int nt=0; nt<8; ++nt){
          const int col = nt*16 + m16;
          if (col < 120){
            #pragma unroll
            for (int rg=0; rg<4; ++rg){
              const int tick = mt*16 + q4*4 + rg;
              dst[tick*120 + col] = acc[mt][nt][rg] + bias_v[nt];
            }
          }
        }
      }
    };

    // prologue: chunk 0 complete before first barrier
    acc_zero();
    chunk_ks(0, 0, 18);
    chunk_store(0);
    __syncthreads();
    #pragma unroll 1
    for (int i=0; i<152; ++i){
      const int c1 = (i>>3) + 1, s = i&7;
      if (c1 <= 18){
        if (s == 0) acc_zero();
        chunk_ks(c1, (s*18)>>3, ((s+1)*18)>>3);   // 2,2,2,3,2,2,2,3 ks
        if (s == 7) chunk_store(c1);
      }
      if ((i & 15) == 2 && i >= 18){
        const int m = (i>>4) - 1;        // window m: ticks 64m..64m+63, parity m&1
        const int t0 = 64*m;
        const int4* src = (const int4*)&hbuf[m&1][0][0];
        #pragma unroll
        for (int q=0; q<10; ++q){
          const int f = q*64 + l;
          const int t = f/10, j4 = f - 10*t;
          int4 v = src[t*10 + j4];
          *(int4*)&hcat[((size_t)bat*600 + t0 + t)*80 + d*40 + j4*4] = v;
        }
      }
      __syncthreads();
    }
  } else {
    // ---------------- compute waves: load role weights into VGPR pairs ----------------
    const void *Wsrc = 0, *bsrc = 0;
    if (w == 0){ Wsrc = d ? b0Whh : f0Whh; bsrc = d ? b0bhh : f0bhh; }
    else if (w == 1){ Wsrc = d ? b1Wih : f1Wih; bsrc = d ? b1bih : f1bih; }
    else { Wsrc = d ? b1Whh : f1Whh; bsrc = d ? b1bhh : f1bhh; }

    float2v WA[20], WB[20], WC[20];
    #pragma unroll
    for (int k=0; k<20; ++k){
      WA[k][0] = lodf(Wsrc, (size_t)(     li)*40 + 2*k,   isbf);
      WA[k][1] = lodf(Wsrc, (size_t)(     li)*40 + 2*k+1, isbf);
      WB[k][0] = lodf(Wsrc, (size_t)(40 + li)*40 + 2*k,   isbf);
      WB[k][1] = lodf(Wsrc, (size_t)(40 + li)*40 + 2*k+1, isbf);
      WC[k][0] = lodf(Wsrc, (size_t)(80 + li)*40 + 2*k,   isbf);
      WC[k][1] = lodf(Wsrc, (size_t)(80 + li)*40 + 2*k+1, isbf);
    }
    float bA = lodf(bsrc, li, isbf), bB = lodf(bsrc, 40+li, isbf), bC = lodf(bsrc, 80+li, isbf);
    float hs = 0.f;

    auto mv3B = [&](const float* hrow, float& oa, float& ob, float& oc){
      float2v a2 = {bA, 0.f}, b2 = {bB, 0.f}, c2 = {bC, 0.f};
      #pragma unroll
      for (int kq=0; kq<10; ++kq){
        const floatx4 hv = *(const floatx4*)(hrow + kq*4);
        float2v h0; h0[0]=hv[0]; h0[1]=hv[1];
        float2v h1; h1[0]=hv[2]; h1[1]=hv[3];
        asm("v_pk_fma_f32 %0, %1, %2, %0" : "+v"(a2) : "v"(WA[2*kq  ]), "v"(h0));
        asm("v_pk_fma_f32 %0, %1, %2, %0" : "+v"(b2) : "v"(WB[2*kq  ]), "v"(h0));
        asm("v_pk_fma_f32 %0, %1, %2, %0" : "+v"(c2) : "v"(WC[2*kq  ]), "v"(h0));
        asm("v_pk_fma_f32 %0, %1, %2, %0" : "+v"(a2) : "v"(WA[2*kq+1]), "v"(h1));
        asm("v_pk_fma_f32 %0, %1, %2, %0" : "+v"(b2) : "v"(WB[2*kq+1]), "v"(h1));
        asm("v_pk_fma_f32 %0, %1, %2, %0" : "+v"(c2) : "v"(WC[2*kq+1]), "v"(h1));
      }
      oa = a2[0] + a2[1]; ob = b2[0] + b2[1]; oc = c2[0] + c2[1];
    };
    auto cellB = [&](const float* hrow, float hsv, float gA, float gB, float gC) -> float {
      float ar, az, an;
      mv3B(hrow, ar, az, an);
      const float r = sigm(gA + ar), z = sigm(gB + az);
      const float n = tanh_(gC + r*an);
      return (1.f - z)*n + z*hsv;
    };

    if (w == 0){
      if (l < 40) h0st[l] = 0.f;
      __syncthreads();
      #pragma unroll 1
      for (int i=0; i<152; ++i){
        PIN_W();
        if (i < 150){
          const int cc = (i>>3)&1;
          const int ta = (4*i)&31;
          const float* base = (const float*)&chunkbuf[cc][0];
          float gin[4][3];
          #pragma unroll
          for (int t=0; t<4; ++t){
            const float* r = base + (d ? (31-(ta+t)) : (ta+t))*120;
            gin[t][0]=r[li]; gin[t][1]=r[40+li]; gin[t][2]=r[80+li];
          }
          #pragma unroll
          for (int t=0; t<4; ++t){
            hs = cellB(h0st, hs, gin[t][0], gin[t][1], gin[t][2]);
            if (l < 40){ h0st[l] = hs; h0buf[i&1][t][l] = hs; }
          }
        }
        __syncthreads();
      }
    } else if (w == 1){
      __syncthreads();
      #pragma unroll 1
      for (int i=0; i<152; ++i){
        PIN_W();
        if (i >= 1 && i <= 150){
          const int p = (i-1)&1;
          #pragma unroll
          for (int t=0; t<4; ++t){
            float oa, ob, oc;
            mv3B(&h0buf[p][t][0], oa, ob, oc);
            if (l < 40){
              gi1buf[i&1][t][0][l]=oa; gi1buf[i&1][t][1][l]=ob; gi1buf[i&1][t][2][l]=oc;
            }
          }
        }
        __syncthreads();
      }
    } else {
      if (l < 40) h1st[l] = 0.f;
      __syncthreads();
      #pragma unroll 1
      for (int i=0; i<152; ++i){
        PIN_W();
        if (i >= 2){
          const int p = (i-1)&1;
          float gin[4][3];
          #pragma unroll
          for (int t=0; t<4; ++t){
            gin[t][0]=gi1buf[p][t][0][li]; gin[t][1]=gi1buf[p][t][1][li]; gin[t][2]=gi1buf[p][t][2][li];
          }
          const int ta2 = 4*(i-2);
          const int wp = (ta2>>6)&1, sa = ta2&63;
          #pragma unroll
          for (int t=0; t<4; ++t){
            hs = cellB(h1st, hs, gin[t][0], gin[t][1], gin[t][2]);
            if (l < 40){ h1st[l] = hs; hbuf[wp][sa+t][l] = hs; }
          }
        }
        __syncthreads();
      }
    }
  }
  // flush final window (ticks 576..599, parity 1)
  if (tid < 240){
    const int t = tid/10, j4 = tid - 10*t;
    const int4* src = (const int4*)&hbuf[1][0][0];
    int4 v = src[t*10 + j4];
    *(int4*)&hcat[((size_t)bat*600 + 576 + t)*80 + d*40 + j4*4] = v;
  }
}

// ============================= KAN: fused kan1+kan2 (unchanged from R10) =====================
__launch_bounds__(256)
__global__ void kan_fused_kernel(const float* __restrict__ Xin,
                                 const u16* __restrict__ B2mat, const u16* __restrict__ B3mat,
                                 void* __restrict__ Obuf,
                                 const void* __restrict__ slope, const int* __restrict__ flag)
{
  __shared__ __attribute__((aligned(16))) float xs[64][84];       // 21504 B (stride 84 dw == 20 mod 32)
  __shared__ __attribute__((aligned(16))) u16 abase[64][200];     // 25600 B (stride 100 dw == 4 mod 32)
  __shared__ __attribute__((aligned(16))) u16 asp1[64][136];      // 17408 B (stride 68 dw == 4 mod 32)
  const int isbf = *flag;
  const int tid = threadIdx.x;
  const size_t r0 = (size_t)blockIdx.x * 64;
  const int w = tid>>6, l = tid&63, m16 = l&15, q4 = l>>4;

  for (int idx=tid; idx<5120; idx+=256){
    const int row = idx/80, m = idx - row*80;
    xs[row][m] = Xin[r0*80 + idx];
  }
  __syncthreads();

  // closed-form uniform cubic B-spline into dst (512 items, 2/thread)
  auto spline_block = [&](int c, u16 (*dst)[136]){
    #pragma unroll
    for (int h=0; h<2; ++h){
      const int idx = tid + h*256;
      const int row = idx>>3, il = idx&7;
      const float xv = xs[row][c*8 + il];
      const float t  = (xv + 2.2f) * 2.5f;          // (x - g0)/h, g0=-2.2, h=0.4
      const float mf = fminf(fmaxf(floorf(t), -4.f), 14.f);
      const int   m  = (int)mf;
      const float u  = t - mf;
      const float u2 = u*u, u3 = u2*u;
      const float i6 = 1.0f/6.0f;
      const float w1mu = 1.f - u;
      const float n0 = w1mu*w1mu*w1mu*i6;
      const float n1 = (3.f*u3 - 6.f*u2 + 4.f)*i6;
      const float n2 = (-3.f*u3 + 3.f*u2 + 3.f*u + 1.f)*i6;
      const float n3 = u3*i6;
      const bool ok = (t >= 0.f) && (t < 11.f);
      union { u16 us[16]; short8 v2[2]; } pk;
      #pragma unroll
      for (int j=0; j<8; ++j){
        const int s = j + 3 - m;
        float v = 0.f;
        v = (s==0) ? n0 : v;
        v = (s==1) ? n1 : v;
        v = (s==2) ? n2 : v;
        v = (s==3) ? n3 : v;
        v = ok ? v : 0.f;
        const u16 hi = f2bf(v);
        pk.us[2*j] = hi; pk.us[2*j+1] = f2bf(v - bf2f(hi));
      }
      *(short8*)&dst[row][il*16]     = pk.v2[0];
      *(short8*)&dst[row][il*16 + 8] = pk.v2[1];
    }
  };

  auto phase = [&](auto ntc, auto fc, const u16* __restrict__ Bmat){
    constexpr int NT   = decltype(ntc)::v;
    constexpr int FINAL = decltype(fc)::v;
    constexpr int MAXC = (NT+3)/4;
    const int cbase = NT>>2, rem = NT&3;
    const int cnt  = cbase + ((w < rem) ? 1 : 0);
    const int ntlo = w*cbase + ((w < rem) ? w : rem);

    short8 bz;
    #pragma unroll
    for (int q=0;q<8;++q) bz[q]=0;
    short8 bcur[MAXC], bmid[MAXC], bnxt[MAXC];
    #pragma unroll
    for (int j=0;j<MAXC;++j){ bcur[j]=bz; bmid[j]=bz; bnxt[j]=bz; }

    #pragma unroll
    for (int j=0;j<MAXC;++j) if (j<cnt){
      bcur[j] = *(const short8*)&Bmat[(size_t)((ntlo+j)*16+m16)*1472 + 0*32 + q4*8];
      bmid[j] = *(const short8*)&Bmat[(size_t)((ntlo+j)*16+m16)*1472 + 1*32 + q4*8];
    }

    for (int idx=tid; idx<6144; idx+=256){
      const int row = idx/96, m = idx - row*96;
      float v = 0.f;
      if (m < 80){ const float xv = xs[row][m]; v = xv * sigm(xv); }
      const u16 hi = f2bf(v);
      abase[row][2*m] = hi; abase[row][2*m+1] = f2bf(v - bf2f(hi));
    }
    __syncthreads();

    floatx4 acc[MAXC][4];
    #pragma unroll
    for (int j=0;j<MAXC;++j) for (int s=0;s<4;++s){ floatx4 z={0.f,0.f,0.f,0.f}; acc[j][s]=z; }

    #pragma unroll 1
    for (int ks=0; ks<6; ++ks){
      if (ks < 4){
        #pragma unroll
        for (int j=0;j<MAXC;++j) if (j<cnt)
          bnxt[j] = *(const short8*)&Bmat[(size_t)((ntlo+j)*16+m16)*1472 + (ks+2)*32 + q4*8];
      }
      short8 a[4];
      #pragma unroll
      for (int s=0;s<4;++s) a[s] = *(const short8*)&abase[s*16+m16][ks*32 + q4*8];
      #pragma unroll
      for (int j=0;j<MAXC;++j){
        if (j < cnt){
          #pragma unroll
          for (int s=0;s<4;++s) acc[j][s] = __builtin_amdgcn_mfma_f32_16x16x32_bf16(a[s], bcur[j], acc[j][s], 0, 0, 0);
        }
      }
      #pragma unroll
      for (int j=0;j<MAXC;++j){ bcur[j]=bmid[j]; bmid[j]=bnxt[j]; }
    }
    __syncthreads();

    #pragma unroll
    for (int j=0;j<MAXC;++j) if (j<cnt){
      bcur[j] = *(const short8*)&Bmat[(size_t)((ntlo+j)*16+m16)*1472 + 192 + 0*128 + 0*32 + q4*8];
      bmid[j] = *(const short8*)&Bmat[(size_t)((ntlo+j)*16+m16)*1472 + 192 + 0*128 + 1*32 + q4*8];
    }
    spline_block(0, (u16(*)[136])&abase[0][0]);
    __syncthreads();

    #pragma unroll 1
    for (int c=0; c<10; ++c){
      if (c < 9) spline_block(c+1, ((c+1)&1) ? asp1 : (u16(*)[136])&abase[0][0]);
      const u16 (*aspr)[136] = (c&1) ? (const u16(*)[136])asp1 : (const u16(*)[136])&abase[0][0];
      #pragma unroll 1
      for (int ks=0; ks<4; ++ks){
        const int pos = c*4 + ks + 2;
        if (pos < 40){
          const int pc = pos>>2, pk = pos&3;
          #pragma unroll
          for (int j=0;j<MAXC;++j) if (j<cnt)
            bnxt[j] = *(const short8*)&Bmat[(size_t)((ntlo+j)*16+m16)*1472 + 192 + pc*128 + pk*32 + q4*8];
        }
        short8 a[4];
        #pragma unroll
        for (int s=0;s<4;++s) a[s] = *(const short8*)&aspr[s*16+m16][ks*32 + q4*8];
        #pragma unroll
        for (int j=0;j<MAXC;++j){
          if (j < cnt){
            #pragma unroll
            for (int s=0;s<4;++s) acc[j][s] = __builtin_amdgcn_mfma_f32_16x16x32_bf16(a[s], bcur[j], acc[j][s], 0, 0, 0);
          }
        }
        #pragma unroll
        for (int j=0;j<MAXC;++j){ bcur[j]=bmid[j]; bmid[j]=bnxt[j]; }
      }
      __syncthreads();
    }

    #pragma unroll
    for (int j=0;j<MAXC;++j){
      if (j < cnt){
        const int col = (ntlo+j)*16 + m16;
        #pragma unroll
        for (int s=0;s<4;++s){
          #pragma unroll
          for (int rg=0; rg<4; ++rg){
            const int row = s*16 + q4*4 + rg;
            const float v = acc[j][s][rg];
            if constexpr (!FINAL){
              xs[row][col] = v;
            } else {
              if (col < 257){
                const float sl = lodf(slope, col, isbf);
                const float o = 1.2f * sigm(sl*v);
                if (isbf) ((u16*)Obuf)[(r0+row)*257 + col] = f2bf(o);
                else      ((float*)Obuf)[(r0+row)*257 + col] = o;
              }
            }
          }
        }
      }
    }
    __syncthreads();
  };

  phase(IC<5>{},  IC<0>{}, B2mat);
  phase(IC<17>{}, IC<1>{}, B3mat);
}

// ============================= launcher =============================
extern "C" void kernel_launch(void* const* d_in, const int* in_sizes, int n_in,
                              void* d_out, int out_size, void* d_ws, size_t ws_size,
                              hipStream_t stream)
{
  (void)in_sizes; (void)n_in; (void)out_size; (void)ws_size;
  const void* x     = d_in[0];
  const void* f0Wih = d_in[2];  const void* f0Whh = d_in[3];
  const void* f0bih = d_in[4];  const void* f0bhh = d_in[5];
  const void* f1Wih = d_in[6];  const void* f1Whh = d_in[7];
  const void* f1bih = d_in[8];  const void* f1bhh = d_in[9];
  const void* b0Wih = d_in[10]; const void* b0Whh = d_in[11];
  const void* b0bih = d_in[12]; const void* b0bhh = d_in[13];
  const void* b1Wih = d_in[14]; const void* b1Whh = d_in[15];
  const void* b1bih = d_in[16]; const void* b1bhh = d_in[17];
  const void* k1b   = d_in[18]; const void* k1s   = d_in[19]; const void* k1sc = d_in[20];
  const void* k2b   = d_in[21]; const void* k2s   = d_in[22]; const void* k2sc = d_in[23];
  const void* slope = d_in[24];

  char* ws = (char*)d_ws;
  int*   flag  = (int*)(ws + OFF_FLAG);
  float* hcat  = (float*)(ws + OFF_HCAT);
  u16* B1a = (u16*)(ws + OFF_B1A);
  u16* B1b = (u16*)(ws + OFF_B1B);
  u16* B2  = (u16*)(ws + OFF_B2);
  u16* B3  = (u16*)(ws + OFF_B3);

  detect_kernel<<<1, 64, 0, stream>>>((const u16*)x, flag);
  prep_kernel<<<1300, 256, 0, stream>>>(f0Wih, b0Wih, k1b, k1s, k1sc, k2b, k2s, k2sc, flag, B1a, B1b, B2, B3);
  gru_kernel<<<128, 256, 0, stream>>>(x, B1a, B1b, f0bih, b0bih,
      f0Whh, f0bhh, f1Wih, f1Whh, f1bih, f1bhh,
      b0Whh, b0bhh, b1Wih, b1Whh, b1bih, b1bhh, flag, hcat);
  kan_fused_kernel<<<600, 256, 0, stream>>>(hcat, B2, B3, d_out, slope, flag);
}